// Round 14
// baseline (27065.173 us; speedup 1.0000x reference)
//
#include <hip/hip_runtime.h>
#include <hip/hip_fp16.h>
#include <math.h>

#define BB    64
#define TT    2048
#define DIN   128
#define HH    512
#define NWG   512     // 2 WGs per CU (TLP hides the serial MALL chain)
#define NTHR  256
#define NUNITS 576    // staged 16B units: x 4*16 + h0 4*64 + h1 4*64

typedef __attribute__((ext_vector_type(4))) unsigned int u32x4;
typedef __attribute__((ext_vector_type(8))) _Float16    f16x8;
typedef __attribute__((ext_vector_type(4))) float       f32x4;
typedef unsigned long long u64;

__device__ __forceinline__ float sigm(float v) { return 1.0f / (1.0f + expf(-v)); }

// ---- MALL (agent-scope) primitives — proven protocol (r4-r10) ----
__device__ __forceinline__ u32x4 ld16m(const void* p) {
  u32x4 v;
  asm volatile("global_load_dwordx4 %0, %1, off sc0 sc1" : "=v"(v) : "v"(p) : "memory");
  return v;
}
__device__ __forceinline__ void st8m(void* p, u64 v) {
  __hip_atomic_store((u64*)p, v, __ATOMIC_RELAXED, __HIP_MEMORY_SCOPE_AGENT);
}
__device__ __forceinline__ u64 ld8m(const void* p) {
  return __hip_atomic_load((const u64*)p, __ATOMIC_RELAXED, __HIP_MEMORY_SCOPE_AGENT);
}
// group barrier (32 arrivals, monotonic counter)
__device__ __forceinline__ void gbar(unsigned* cnt, unsigned target, int* dead) {
  __syncthreads();
  if (threadIdx.x == 0 && *dead == 0) {
    asm volatile("s_waitcnt vmcnt(0)" ::: "memory");   // h-stores MALL-ack'd first
    __hip_atomic_fetch_add(cnt, 1u, __ATOMIC_RELAXED, __HIP_MEMORY_SCOPE_AGENT);
    long sp = 0;
    while (__hip_atomic_load(cnt, __ATOMIC_RELAXED, __HIP_MEMORY_SCOPE_AGENT) < target) {
      __builtin_amdgcn_s_sleep(1);
      if (++sp > (1L << 22)) { *dead = 1; break; }     // no-hang valve
    }
    asm volatile("" ::: "memory");
  }
  __syncthreads();
}

// ---- prep kernels -----------------------------------------------------------
__global__ __launch_bounds__(64, 1) void prep_flush() {
  extern __shared__ char dummy[];
  if (threadIdx.x == 0) { __threadfence(); dummy[0] = 0; }
  __syncthreads();
}
__global__ void prep_zero(unsigned* w) {
  const int total = (4*BB*HH*2 + 4096) / 4;   // h region + barrier words
  for (int i = blockIdx.x*blockDim.x + threadIdx.x; i < total; i += gridDim.x*blockDim.x)
    __hip_atomic_store(w + i, 0u, __ATOMIC_RELAXED, __HIP_MEMORY_SCOPE_AGENT);
}
__global__ void xcvt(const float* __restrict__ x, u64* __restrict__ xh) {
  const int N4 = BB*TT*DIN/4;
  const float4* x4 = reinterpret_cast<const float4*>(x);
  for (int i = blockIdx.x*blockDim.x + threadIdx.x; i < N4; i += gridDim.x*blockDim.x) {
    float4 v = x4[i];
    __half2 a = __floats2half2_rn(v.x, v.y);
    __half2 b = __floats2half2_rn(v.z, v.w);
    u64 u = ((u64)__builtin_bit_cast(unsigned, b) << 32) | (u64)__builtin_bit_cast(unsigned, a);
    __hip_atomic_store(&xh[i], u, __ATOMIC_RELAXED, __HIP_MEMORY_SCOPE_AGENT);
  }
}

__global__ __launch_bounds__(NTHR, 2) void lstm2_tlp(
    const float* __restrict__ Wih0, const float* __restrict__ Whh0,
    const float* __restrict__ bih0, const float* __restrict__ bhh0,
    const float* __restrict__ Wih1, const float* __restrict__ Whh1,
    const float* __restrict__ bih1, const float* __restrict__ bhh1,
    const float* __restrict__ fcw,  const float* __restrict__ fcb,
    float* __restrict__ out, float* __restrict__ ws)
{
  extern __shared__ char smbase[];                          // 576*16 = 9216 B staging
  __half* hout = reinterpret_cast<__half*>(smbase + 9216);  // [2][4][16] halves (256 B)
  int*    dead = reinterpret_cast<int*>(smbase + 9216 + 256);

  const int tid  = threadIdx.x;
  const int wg   = blockIdx.x;
  const int lane = tid & 63;
  const int wv   = tid >> 6;

  const int grp  = wg >> 5;        // 16 groups of 4 batches
  const int r    = wg & 31;        // rank -> h-cols [16r,16r+16)
  const int bg4  = grp * 4;
  const int c0   = 16*r + 4*wv;    // wave's 4 h-cols per layer

  __half* h0s = reinterpret_cast<__half*>(ws);     // 2 x [64][512] fp16
  __half* h1s = h0s + 2*BB*HH;
  unsigned* gcnt = reinterpret_cast<unsigned*>(reinterpret_cast<char*>(ws) + 262144) + grp*32;
  const __half* xh = reinterpret_cast<const __half*>(reinterpret_cast<char*>(ws) + 524288);

  // A-fragments, rt = jc*4 + gate (transpose-free epilogue, verified r10)
  const int rt   = lane & 15;
  const int gate = rt & 3;
  const int jc   = rt >> 2;
  const int kg   = lane >> 4;
  const int b15  = lane & 15;
  const int n0   = gate*HH + (c0 + jc);

  f16x8 af0[20];   // L0: K=640 = [x 0-127 | h0 128-639]
#pragma unroll
  for (int m = 0; m < 20; ++m) {
    int k0 = 32*m + 8*kg;
    const float* srcp = (k0 < DIN) ? (Wih0 + (size_t)n0*DIN + k0)
                                   : (Whh0 + (size_t)n0*HH + (k0 - DIN));
    float4 a = *reinterpret_cast<const float4*>(srcp);
    float4 b = *reinterpret_cast<const float4*>(srcp + 4);
    f16x8 fr;
    fr[0]=(_Float16)a.x; fr[1]=(_Float16)a.y; fr[2]=(_Float16)a.z; fr[3]=(_Float16)a.w;
    fr[4]=(_Float16)b.x; fr[5]=(_Float16)b.y; fr[6]=(_Float16)b.z; fr[7]=(_Float16)b.w;
    af0[m] = fr;
  }
  f16x8 af1[32];   // L1: K=1024 = [h0 (W_ih1) | h1 (W_hh1)]
#pragma unroll
  for (int m = 0; m < 32; ++m) {
    int k0 = 32*m + 8*kg;
    const float* srcp = (k0 < HH) ? (Wih1 + (size_t)n0*HH + k0)
                                  : (Whh1 + (size_t)n0*HH + (k0 - HH));
    float4 a = *reinterpret_cast<const float4*>(srcp);
    float4 b = *reinterpret_cast<const float4*>(srcp + 4);
    f16x8 fr;
    fr[0]=(_Float16)a.x; fr[1]=(_Float16)a.y; fr[2]=(_Float16)a.z; fr[3]=(_Float16)a.w;
    fr[4]=(_Float16)b.x; fr[5]=(_Float16)b.y; fr[6]=(_Float16)b.z; fr[7]=(_Float16)b.w;
    af1[m] = fr;
  }

  const int cmy = c0 + kg;            // this lane's h-column
  float bv0[4], bv1[4];
#pragma unroll
  for (int g = 0; g < 4; ++g) {
    bv0[g] = bih0[g*HH + cmy] + bhh0[g*HH + cmy];
    bv1[g] = bih1[g*HH + cmy] + bhh1[g*HH + cmy];
  }

  float cst0 = 0.f, cst1 = 0.f;
  const int beff = (b15 < 4) ? b15 : 3;   // B-frag batch clamp (4 real batches)
  if (tid == 0) *dead = 0;
  __syncthreads();

  for (int st = 0; st <= TT; ++st) {
    const int tcur = (st < TT) ? st : (TT - 1);
    const __half* h0r = h0s + (size_t)(st & 1)*BB*HH;
    const __half* h1r = h1s + (size_t)(st & 1)*BB*HH;

    // ---- stage x-slice + group h0 + h1 into LDS (9 KB, XOR-swizzled) ----
    u32x4 stgL[3];
    int   physv[3];
#pragma unroll
    for (int ii = 0; ii < 3; ++ii) {
      int idx = tid + NTHR*ii;
      physv[ii] = -1;
      if (idx < NUNITS) {
        const __half* src; int phys;
        if (idx < 64)       { int b = idx>>4, u = idx&15;
          src = xh + (size_t)(bg4+b)*TT*DIN + (size_t)tcur*DIN + u*8;
          phys = b*16 + (u ^ b); }
        else if (idx < 320) { int i2 = idx-64,  b = i2>>6, u = i2&63;
          src = h0r + (size_t)(bg4+b)*HH + u*8;
          phys = 64 + b*64 + (u ^ b); }
        else                { int i2 = idx-320, b = i2>>6, u = i2&63;
          src = h1r + (size_t)(bg4+b)*HH + u*8;
          phys = 320 + b*64 + (u ^ b); }
        physv[ii] = phys;
        stgL[ii] = ld16m(src);
      }
    }
    asm volatile("s_waitcnt vmcnt(0)" ::: "memory");
    __builtin_amdgcn_sched_barrier(0);
#pragma unroll
    for (int ii = 0; ii < 3; ++ii)
      if (physv[ii] >= 0)
        *reinterpret_cast<u32x4*>(smbase + physv[ii]*16) = stgL[ii];
    __syncthreads();

    // ---- MFMA: L0 (20) + L1 (32), 2-way acc split ----
    f32x4 a0a = {0.f,0.f,0.f,0.f}, a0b = a0a, a1a = a0a, a1b = a0a;
#pragma unroll
    for (int m = 0; m < 20; ++m) {
      int phys = (m < 4) ? (beff*16 + ((4*m + kg) ^ beff))
                         : (64 + beff*64 + ((4*(m-4) + kg) ^ beff));
      f16x8 bf = *reinterpret_cast<const f16x8*>(smbase + phys*16);
      if (m & 1) a0b = __builtin_amdgcn_mfma_f32_16x16x32_f16(af0[m], bf, a0b, 0, 0, 0);
      else       a0a = __builtin_amdgcn_mfma_f32_16x16x32_f16(af0[m], bf, a0a, 0, 0, 0);
    }
#pragma unroll
    for (int m = 0; m < 32; ++m) {
      int phys = (m < 16) ? (64 + beff*64 + ((4*m + kg) ^ beff))
                          : (320 + beff*64 + ((4*(m-16) + kg) ^ beff));
      f16x8 bf = *reinterpret_cast<const f16x8*>(smbase + phys*16);
      if (m & 1) a1b = __builtin_amdgcn_mfma_f32_16x16x32_f16(af1[m], bf, a1b, 0, 0, 0);
      else       a1a = __builtin_amdgcn_mfma_f32_16x16x32_f16(af1[m], bf, a1a, 0, 0, 0);
    }
    f32x4 a0 = a0a + a0b;
    f32x4 a1 = a1a + a1b;

    // ---- gates directly from acc (a[j] = gate j of (col cmy, batch b15)) ----
    if (st < TT) {
      float gi = sigm (a0[0] + bv0[0]);
      float gf = sigm (a0[1] + bv0[1]);
      float gg = tanhf(a0[2] + bv0[2]);
      float go = sigm (a0[3] + bv0[3]);
      cst0 = gf*cst0 + gi*gg;
      float hn = go * tanhf(cst0);
      if (b15 < 4) hout[0*64 + b15*16 + 4*wv + kg] = __float2half(hn);
    }
    if (st >= 1) {
      float gi = sigm (a1[0] + bv1[0]);
      float gf = sigm (a1[1] + bv1[1]);
      float gg = tanhf(a1[2] + bv1[2]);
      float go = sigm (a1[3] + bv1[3]);
      cst1 = gf*cst1 + gi*gg;
      float hn = go * tanhf(cst1);
      if (b15 < 4) hout[1*64 + b15*16 + 4*wv + kg] = __float2half(hn);
    }
    __syncthreads();

    // ---- pack-store h (tid<32: 2 layers x 4 batches x 4 parts, 8B each) ----
    if (tid < 32) {
      int layer = tid >> 4, q = tid & 15, b = q >> 2, part = q & 3;
      bool do_st = (layer == 0) ? (st < TT) : (st >= 1);
      if (do_st) {
        u64 v = *reinterpret_cast<u64*>(hout + layer*64 + b*16 + part*4);
        __half* base = (layer ? h1s : h0s) + (size_t)((st + 1) & 1)*BB*HH;
        st8m(base + (size_t)(bg4+b)*HH + 16*r + part*4, v);
      }
    }
    gbar(gcnt, 32u*(unsigned)(st + 1), dead);
  }

  // ---- FC on final h1 (parity 1): 16 outputs/WG, 16 threads per output,
  //      each thread covers 8 u64 = 32 halves (16*32 = 512 = HH exactly) ----
  {
    const __half* h1f = h1s + (size_t)BB*HH;
    int oi = tid >> 4, kp = tid & 15;
    int b  = oi >> 2, cc = oi & 3;
    int ocol = 4*r + cc;
    const u64* h8 = reinterpret_cast<const u64*>(h1f + (size_t)(bg4+b)*HH) + kp*8;
    const float* wrow = fcw + (size_t)ocol*HH + kp*32;
    float p = 0.f;
#pragma unroll
    for (int kk = 0; kk < 8; ++kk) {
      u64 v = ld8m(h8 + kk);
      __half2 hlo = __builtin_bit_cast(__half2, (unsigned)(v & 0xffffffffull));
      __half2 hhi = __builtin_bit_cast(__half2, (unsigned)(v >> 32));
      float2 flo = __half22float2(hlo), fhi = __half22float2(hhi);
      float4 w = *reinterpret_cast<const float4*>(wrow + kk*4);
      p += flo.x*w.x + flo.y*w.y + fhi.x*w.z + fhi.y*w.w;
    }
    p += __shfl_xor(p, 1);
    p += __shfl_xor(p, 2);
    p += __shfl_xor(p, 4);
    p += __shfl_xor(p, 8);
    if (kp == 0) out[(size_t)(bg4+b)*128 + ocol] = p + fcb[ocol];
  }
}

__global__ void sentinel_fail(float* out, float v) { out[threadIdx.x] = v; }

extern "C" void kernel_launch(void* const* d_in, const int* in_sizes, int n_in,
                              void* d_out, int out_size, void* d_ws, size_t ws_size,
                              hipStream_t stream) {
  const float* x    = (const float*)d_in[0];
  const float* Wih0 = (const float*)d_in[1];
  const float* Whh0 = (const float*)d_in[2];
  const float* bih0 = (const float*)d_in[3];
  const float* bhh0 = (const float*)d_in[4];
  const float* Wih1 = (const float*)d_in[5];
  const float* Whh1 = (const float*)d_in[6];
  const float* bih1 = (const float*)d_in[7];
  const float* bhh1 = (const float*)d_in[8];
  const float* fcw  = (const float*)d_in[9];
  const float* fcb  = (const float*)d_in[10];
  float* out = (float*)d_out;
  float* ws  = (float*)d_ws;
  (void)in_sizes; (void)n_in; (void)out_size;

  const size_t need = 524288 + (size_t)BB*TT*DIN*2;
  if (ws_size < need) {
    sentinel_fail<<<1, 128, 0, stream>>>(out, 2.0e6f);
    return;
  }

  const int flush_smem = 108*1024;   // forces 1 WG/CU for the flush kernel
  const int main_smem  = 54*1024;    // caps main kernel at exactly 2 WGs/CU
  hipFuncSetAttribute(reinterpret_cast<const void*>(&lstm2_tlp),
                      hipFuncAttributeMaxDynamicSharedMemorySize, main_smem);
  hipFuncSetAttribute(reinterpret_cast<const void*>(&prep_flush),
                      hipFuncAttributeMaxDynamicSharedMemorySize, flush_smem);

  (void)hipGetLastError();
  prep_flush<<<dim3(256), dim3(64), flush_smem, stream>>>();
  xcvt<<<dim3(2048), dim3(NTHR), 0, stream>>>(
      x, reinterpret_cast<u64*>(reinterpret_cast<char*>(d_ws) + 524288));
  prep_zero<<<dim3(256), dim3(NTHR), 0, stream>>>((unsigned*)d_ws);
  lstm2_tlp<<<dim3(NWG), dim3(NTHR), main_smem, stream>>>(
      Wih0, Whh0, bih0, bhh0, Wih1, Whh1, bih1, bhh1, fcw, fcb, out, ws);
  hipError_t e = hipGetLastError();
  if (e != hipSuccess) {
    sentinel_fail<<<1, 128, 0, stream>>>(out, 1.0e6f);
  }
}

// Round 15
// 8324.832 us; speedup vs baseline: 3.2511x; 3.2511x over previous
//
#include <hip/hip_runtime.h>
#include <hip/hip_fp16.h>
#include <math.h>

#define BB    64
#define TT    2048
#define DIN   128
#define HH    512
#define NTHR  256

typedef __attribute__((ext_vector_type(4))) unsigned int u32x4;
typedef __attribute__((ext_vector_type(8))) _Float16    f16x8;
typedef __attribute__((ext_vector_type(4))) float       f32x4;
typedef unsigned long long u64;

__device__ __forceinline__ float sigm(float v) { return 1.0f / (1.0f + expf(-v)); }

// ---- MALL (agent-scope) primitives — proven protocol (r4-r10) ----
__device__ __forceinline__ u32x4 ld16m(const void* p) {
  u32x4 v;
  asm volatile("global_load_dwordx4 %0, %1, off sc0 sc1" : "=v"(v) : "v"(p) : "memory");
  return v;
}
__device__ __forceinline__ void st8m(void* p, u64 v) {
  __hip_atomic_store((u64*)p, v, __ATOMIC_RELAXED, __HIP_MEMORY_SCOPE_AGENT);
}
__device__ __forceinline__ u64 ld8m(const void* p) {
  return __hip_atomic_load((const u64*)p, __ATOMIC_RELAXED, __HIP_MEMORY_SCOPE_AGENT);
}
__device__ __forceinline__ void gbar(unsigned* cnt, unsigned target, int* dead) {
  __syncthreads();
  if (threadIdx.x == 0 && *dead == 0) {
    asm volatile("s_waitcnt vmcnt(0)" ::: "memory");   // h-stores MALL-ack'd first
    __hip_atomic_fetch_add(cnt, 1u, __ATOMIC_RELAXED, __HIP_MEMORY_SCOPE_AGENT);
    long sp = 0;
    while (__hip_atomic_load(cnt, __ATOMIC_RELAXED, __HIP_MEMORY_SCOPE_AGENT) < target) {
      __builtin_amdgcn_s_sleep(1);
      if (++sp > (1L << 22)) { *dead = 1; break; }     // no-hang valve
    }
    asm volatile("" ::: "memory");
  }
  __syncthreads();
}

// ---- prep kernels -----------------------------------------------------------
__global__ __launch_bounds__(64, 1) void prep_flush() {
  extern __shared__ char dummy[];
  if (threadIdx.x == 0) { __threadfence(); dummy[0] = 0; }
  __syncthreads();
}
__global__ void prep_zero(unsigned* w) {
  const int total = (4*BB*HH*2 + 4096) / 4;   // h region + barrier words
  for (int i = blockIdx.x*blockDim.x + threadIdx.x; i < total; i += gridDim.x*blockDim.x)
    __hip_atomic_store(w + i, 0u, __ATOMIC_RELAXED, __HIP_MEMORY_SCOPE_AGENT);
}
__global__ void xcvt(const float* __restrict__ x, u64* __restrict__ xh) {
  const int N4 = BB*TT*DIN/4;
  const float4* x4 = reinterpret_cast<const float4*>(x);
  for (int i = blockIdx.x*blockDim.x + threadIdx.x; i < N4; i += gridDim.x*blockDim.x) {
    float4 v = x4[i];
    __half2 a = __floats2half2_rn(v.x, v.y);
    __half2 b = __floats2half2_rn(v.z, v.w);
    u64 u = ((u64)__builtin_bit_cast(unsigned, b) << 32) | (u64)__builtin_bit_cast(unsigned, a);
    __hip_atomic_store(&xh[i], u, __ATOMIC_RELAXED, __HIP_MEMORY_SCOPE_AGENT);
  }
}

// BPG = batches per group. Grid = (64/BPG) groups x 32 WGs.
// BPG=8: 256 WGs, 1/CU (r10-proven). BPG=4: 512 WGs, 2/CU (TLP).
template<int BPG>
__global__ __launch_bounds__(NTHR, 1) void lstm2_k(
    const float* __restrict__ Wih0, const float* __restrict__ Whh0,
    const float* __restrict__ bih0, const float* __restrict__ bhh0,
    const float* __restrict__ Wih1, const float* __restrict__ Whh1,
    const float* __restrict__ bih1, const float* __restrict__ bhh1,
    const float* __restrict__ fcw,  const float* __restrict__ fcb,
    float* __restrict__ out, float* __restrict__ ws)
{
  constexpr int NUNITS = BPG * 144;          // x BPG*16 + h0 BPG*64 + h1 BPG*64
  constexpr int NITER  = (NUNITS + NTHR - 1) / NTHR;
  constexpr int XB     = BPG * 16;           // h0 region base (16B units)
  constexpr int H1B    = XB + BPG * 64;      // h1 region base

  extern __shared__ char smbase[];
  __half* hout = reinterpret_cast<__half*>(smbase + NUNITS*16);  // [2][BPG][16]
  int*    dead = reinterpret_cast<int*>(smbase + NUNITS*16 + 2*BPG*16*2);

  const int tid  = threadIdx.x;
  const int wg   = blockIdx.x;
  const int lane = tid & 63;
  const int wv   = tid >> 6;

  const int grp  = wg >> 5;        // batch group
  const int r    = wg & 31;        // rank -> h-cols [16r,16r+16)
  const int bg   = grp * BPG;
  const int c0   = 16*r + 4*wv;

  __half* h0s = reinterpret_cast<__half*>(ws);     // 2 x [64][512] fp16
  __half* h1s = h0s + 2*BB*HH;
  unsigned* gcnt = reinterpret_cast<unsigned*>(reinterpret_cast<char*>(ws) + 262144) + grp*32;
  const __half* xh = reinterpret_cast<const __half*>(reinterpret_cast<char*>(ws) + 524288);

  // A-fragments, rt = jc*4 + gate (transpose-free epilogue, verified r10)
  const int rt   = lane & 15;
  const int gate = rt & 3;
  const int jc   = rt >> 2;
  const int kg   = lane >> 4;
  const int b15  = lane & 15;
  const int n0   = gate*HH + (c0 + jc);

  f16x8 af0[20];   // L0: K=640 = [x 0-127 | h0 128-639]
#pragma unroll
  for (int m = 0; m < 20; ++m) {
    int k0 = 32*m + 8*kg;
    const float* srcp = (k0 < DIN) ? (Wih0 + (size_t)n0*DIN + k0)
                                   : (Whh0 + (size_t)n0*HH + (k0 - DIN));
    float4 a = *reinterpret_cast<const float4*>(srcp);
    float4 b = *reinterpret_cast<const float4*>(srcp + 4);
    f16x8 fr;
    fr[0]=(_Float16)a.x; fr[1]=(_Float16)a.y; fr[2]=(_Float16)a.z; fr[3]=(_Float16)a.w;
    fr[4]=(_Float16)b.x; fr[5]=(_Float16)b.y; fr[6]=(_Float16)b.z; fr[7]=(_Float16)b.w;
    af0[m] = fr;
  }
  f16x8 af1[32];   // L1: K=1024 = [h0 (W_ih1) | h1 (W_hh1)]
#pragma unroll
  for (int m = 0; m < 32; ++m) {
    int k0 = 32*m + 8*kg;
    const float* srcp = (k0 < HH) ? (Wih1 + (size_t)n0*HH + k0)
                                  : (Whh1 + (size_t)n0*HH + (k0 - HH));
    float4 a = *reinterpret_cast<const float4*>(srcp);
    float4 b = *reinterpret_cast<const float4*>(srcp + 4);
    f16x8 fr;
    fr[0]=(_Float16)a.x; fr[1]=(_Float16)a.y; fr[2]=(_Float16)a.z; fr[3]=(_Float16)a.w;
    fr[4]=(_Float16)b.x; fr[5]=(_Float16)b.y; fr[6]=(_Float16)b.z; fr[7]=(_Float16)b.w;
    af1[m] = fr;
  }

  const int cmy = c0 + kg;
  float bv0[4], bv1[4];
#pragma unroll
  for (int g = 0; g < 4; ++g) {
    bv0[g] = bih0[g*HH + cmy] + bhh0[g*HH + cmy];
    bv1[g] = bih1[g*HH + cmy] + bhh1[g*HH + cmy];
  }

  float cst0 = 0.f, cst1 = 0.f;
  const int beff = (b15 < BPG) ? b15 : (BPG - 1);   // B-frag batch clamp
  if (tid == 0) *dead = 0;
  __syncthreads();

  for (int st = 0; st <= TT; ++st) {
    const int tcur = (st < TT) ? st : (TT - 1);
    const __half* h0r = h0s + (size_t)(st & 1)*BB*HH;
    const __half* h1r = h1s + (size_t)(st & 1)*BB*HH;

    // ---- stage x-slice + group h0 + h1 into LDS (XOR-swizzled) ----
    u32x4 stgL[NITER];
    int   physv[NITER];
#pragma unroll
    for (int ii = 0; ii < NITER; ++ii) {
      int idx = tid + NTHR*ii;
      physv[ii] = -1;
      if (idx < NUNITS) {
        const __half* src; int phys;
        if (idx < XB)       { int b = idx>>4, u = idx&15;
          src = xh + (size_t)(bg+b)*TT*DIN + (size_t)tcur*DIN + u*8;
          phys = b*16 + (u ^ b); }
        else if (idx < H1B) { int i2 = idx-XB,  b = i2>>6, u = i2&63;
          src = h0r + (size_t)(bg+b)*HH + u*8;
          phys = XB + b*64 + (u ^ b); }
        else                { int i2 = idx-H1B, b = i2>>6, u = i2&63;
          src = h1r + (size_t)(bg+b)*HH + u*8;
          phys = H1B + b*64 + (u ^ b); }
        physv[ii] = phys;
        stgL[ii] = ld16m(src);
      }
    }
    asm volatile("s_waitcnt vmcnt(0)" ::: "memory");
    __builtin_amdgcn_sched_barrier(0);
#pragma unroll
    for (int ii = 0; ii < NITER; ++ii)
      if (physv[ii] >= 0)
        *reinterpret_cast<u32x4*>(smbase + physv[ii]*16) = stgL[ii];
    __syncthreads();

    // ---- MFMA: L0 (20) + L1 (32), 2-way acc split ----
    f32x4 a0a = {0.f,0.f,0.f,0.f}, a0b = a0a, a1a = a0a, a1b = a0a;
#pragma unroll
    for (int m = 0; m < 20; ++m) {
      int phys = (m < 4) ? (beff*16 + ((4*m + kg) ^ beff))
                         : (XB + beff*64 + ((4*(m-4) + kg) ^ beff));
      f16x8 bf = *reinterpret_cast<const f16x8*>(smbase + phys*16);
      if (m & 1) a0b = __builtin_amdgcn_mfma_f32_16x16x32_f16(af0[m], bf, a0b, 0, 0, 0);
      else       a0a = __builtin_amdgcn_mfma_f32_16x16x32_f16(af0[m], bf, a0a, 0, 0, 0);
    }
#pragma unroll
    for (int m = 0; m < 32; ++m) {
      int phys = (m < 16) ? (XB + beff*64 + ((4*m + kg) ^ beff))
                          : (H1B + beff*64 + ((4*(m-16) + kg) ^ beff));
      f16x8 bf = *reinterpret_cast<const f16x8*>(smbase + phys*16);
      if (m & 1) a1b = __builtin_amdgcn_mfma_f32_16x16x32_f16(af1[m], bf, a1b, 0, 0, 0);
      else       a1a = __builtin_amdgcn_mfma_f32_16x16x32_f16(af1[m], bf, a1a, 0, 0, 0);
    }
    f32x4 a0 = a0a + a0b;
    f32x4 a1 = a1a + a1b;

    // ---- gates directly from acc (a[j] = gate j of (col cmy, batch b15)) ----
    if (st < TT) {
      float gi = sigm (a0[0] + bv0[0]);
      float gf = sigm (a0[1] + bv0[1]);
      float gg = tanhf(a0[2] + bv0[2]);
      float go = sigm (a0[3] + bv0[3]);
      cst0 = gf*cst0 + gi*gg;
      float hn = go * tanhf(cst0);
      if (b15 < BPG) hout[0*(BPG*16) + b15*16 + 4*wv + kg] = __float2half(hn);
    }
    if (st >= 1) {
      float gi = sigm (a1[0] + bv1[0]);
      float gf = sigm (a1[1] + bv1[1]);
      float gg = tanhf(a1[2] + bv1[2]);
      float go = sigm (a1[3] + bv1[3]);
      cst1 = gf*cst1 + gi*gg;
      float hn = go * tanhf(cst1);
      if (b15 < BPG) hout[1*(BPG*16) + b15*16 + 4*wv + kg] = __float2half(hn);
    }
    __syncthreads();

    // ---- pack-store h (2 layers x BPG batches x 4 parts, 8B each) ----
    if (tid < 2*BPG*4) {
      int layer = tid / (BPG*4), q = tid % (BPG*4), b = q >> 2, part = q & 3;
      bool do_st = (layer == 0) ? (st < TT) : (st >= 1);
      if (do_st) {
        u64 v = *reinterpret_cast<u64*>(hout + layer*(BPG*16) + b*16 + part*4);
        __half* base = (layer ? h1s : h0s) + (size_t)((st + 1) & 1)*BB*HH;
        st8m(base + (size_t)(bg+b)*HH + 16*r + part*4, v);
      }
    }
    gbar(gcnt, 32u*(unsigned)(st + 1), dead);
  }

  // ---- FC on final h1 (parity 1): 4*BPG outputs/WG, TPO threads each ----
  {
    constexpr int TPO = 64 / BPG;          // threads per output (8 or 16)
    constexpr int UPT = 128 / TPO;         // u64 per thread (16 or 8); TPO*UPT = 128 = HH u64s
    const __half* h1f = h1s + (size_t)BB*HH;
    int oi = tid / TPO, kp = tid % TPO;
    int b  = oi >> 2, cc = oi & 3;
    int ocol = 4*r + cc;
    const u64* h8 = reinterpret_cast<const u64*>(h1f + (size_t)(bg+b)*HH) + kp*UPT;
    const float* wrow = fcw + (size_t)ocol*HH + kp*(UPT*4);
    float p = 0.f;
#pragma unroll
    for (int kk = 0; kk < UPT; ++kk) {
      u64 v = ld8m(h8 + kk);
      __half2 hlo = __builtin_bit_cast(__half2, (unsigned)(v & 0xffffffffull));
      __half2 hhi = __builtin_bit_cast(__half2, (unsigned)(v >> 32));
      float2 flo = __half22float2(hlo), fhi = __half22float2(hhi);
      float4 w = *reinterpret_cast<const float4*>(wrow + kk*4);
      p += flo.x*w.x + flo.y*w.y + fhi.x*w.z + fhi.y*w.w;
    }
    p += __shfl_xor(p, 1);
    p += __shfl_xor(p, 2);
    p += __shfl_xor(p, 4);
    if (TPO == 16) p += __shfl_xor(p, 8);
    if (kp == 0 && b < BPG) out[(size_t)(bg+b)*128 + ocol] = p + fcb[ocol];
  }
}

__global__ void sentinel_fail(float* out, float v) { out[threadIdx.x] = v; }

extern "C" void kernel_launch(void* const* d_in, const int* in_sizes, int n_in,
                              void* d_out, int out_size, void* d_ws, size_t ws_size,
                              hipStream_t stream) {
  const float* x    = (const float*)d_in[0];
  const float* Wih0 = (const float*)d_in[1];
  const float* Whh0 = (const float*)d_in[2];
  const float* bih0 = (const float*)d_in[3];
  const float* bhh0 = (const float*)d_in[4];
  const float* Wih1 = (const float*)d_in[5];
  const float* Whh1 = (const float*)d_in[6];
  const float* bih1 = (const float*)d_in[7];
  const float* bhh1 = (const float*)d_in[8];
  const float* fcw  = (const float*)d_in[9];
  const float* fcb  = (const float*)d_in[10];
  float* out = (float*)d_out;
  float* ws  = (float*)d_ws;
  (void)in_sizes; (void)n_in; (void)out_size;

  const size_t need = 524288 + (size_t)BB*TT*DIN*2;
  if (ws_size < need) {
    sentinel_fail<<<1, 128, 0, stream>>>(out, 2.0e6f);
    return;
  }

  const int flush_smem = 108*1024;
  const int smem4 = 54*1024;    // BPG=4 kernel: allows exactly 2 WGs/CU by LDS
  const int smem8 = 108*1024;   // BPG=8 kernel: forces 1 WG/CU (r10-proven)
  hipFuncSetAttribute(reinterpret_cast<const void*>(&lstm2_k<4>),
                      hipFuncAttributeMaxDynamicSharedMemorySize, smem4);
  hipFuncSetAttribute(reinterpret_cast<const void*>(&lstm2_k<8>),
                      hipFuncAttributeMaxDynamicSharedMemorySize, smem8);
  hipFuncSetAttribute(reinterpret_cast<const void*>(&prep_flush),
                      hipFuncAttributeMaxDynamicSharedMemorySize, flush_smem);

  // Occupancy gate: only take the 512-WG TLP path if 2 WGs/CU actually fit
  // (VGPR + LDS). Otherwise the proven 256-WG config — never a deadlock.
  int occ = 0;
  hipError_t qe = hipOccupancyMaxActiveBlocksPerMultiprocessor(
      &occ, reinterpret_cast<const void*>(&lstm2_k<4>), NTHR, smem4);
  const bool tlp = (qe == hipSuccess && occ >= 2);

  (void)hipGetLastError();
  prep_flush<<<dim3(256), dim3(64), flush_smem, stream>>>();
  xcvt<<<dim3(2048), dim3(NTHR), 0, stream>>>(
      x, reinterpret_cast<u64*>(reinterpret_cast<char*>(d_ws) + 524288));
  prep_zero<<<dim3(256), dim3(NTHR), 0, stream>>>((unsigned*)d_ws);
  if (tlp)
    lstm2_k<4><<<dim3(512), dim3(NTHR), smem4, stream>>>(
        Wih0, Whh0, bih0, bhh0, Wih1, Whh1, bih1, bhh1, fcw, fcb, out, ws);
  else
    lstm2_k<8><<<dim3(256), dim3(NTHR), smem8, stream>>>(
        Wih0, Whh0, bih0, bhh0, Wih1, Whh1, bih1, bhh1, fcw, fcb, out, ws);
  hipError_t e = hipGetLastError();
  if (e != hipSuccess) {
    sentinel_fail<<<1, 128, 0, stream>>>(out, 1.0e6f);
  }
}

// Round 16
// 8320.619 us; speedup vs baseline: 3.2528x; 1.0005x over previous
//
#include <hip/hip_runtime.h>
#include <hip/hip_fp16.h>
#include <math.h>

#define BB    64
#define TT    2048
#define DIN   128
#define HH    512
#define NTHR  256

typedef __attribute__((ext_vector_type(4))) unsigned int u32x4;
typedef __attribute__((ext_vector_type(8))) _Float16    f16x8;
typedef __attribute__((ext_vector_type(4))) float       f32x4;
typedef unsigned long long u64;

__device__ __forceinline__ float sigm(float v) { return 1.0f / (1.0f + expf(-v)); }

// ---- MALL (agent-scope) primitives — proven protocol (r4-r10) ----
__device__ __forceinline__ u32x4 ld16m(const void* p) {
  u32x4 v;
  asm volatile("global_load_dwordx4 %0, %1, off sc0 sc1" : "=v"(v) : "v"(p) : "memory");
  return v;
}
__device__ __forceinline__ void st8m(void* p, u64 v) {
  __hip_atomic_store((u64*)p, v, __ATOMIC_RELAXED, __HIP_MEMORY_SCOPE_AGENT);
}
__device__ __forceinline__ u64 ld8m(const void* p) {
  return __hip_atomic_load((const u64*)p, __ATOMIC_RELAXED, __HIP_MEMORY_SCOPE_AGENT);
}
__device__ __forceinline__ void gbar(unsigned* cnt, unsigned target, int* dead) {
  __syncthreads();
  if (threadIdx.x == 0 && *dead == 0) {
    asm volatile("s_waitcnt vmcnt(0)" ::: "memory");   // h-stores MALL-ack'd first
    __hip_atomic_fetch_add(cnt, 1u, __ATOMIC_RELAXED, __HIP_MEMORY_SCOPE_AGENT);
    long sp = 0;
    while (__hip_atomic_load(cnt, __ATOMIC_RELAXED, __HIP_MEMORY_SCOPE_AGENT) < target) {
      __builtin_amdgcn_s_sleep(1);
      if (++sp > (1L << 22)) { *dead = 1; break; }     // no-hang valve
    }
    asm volatile("" ::: "memory");
  }
  __syncthreads();
}

// ---- prep kernels -----------------------------------------------------------
__global__ __launch_bounds__(64, 1) void prep_flush() {
  extern __shared__ char dummy[];
  if (threadIdx.x == 0) { __threadfence(); dummy[0] = 0; }
  __syncthreads();
}
__global__ void prep_zero(unsigned* w) {
  const int total = (4*BB*HH*2 + 4096) / 4;   // h region + barrier words
  for (int i = blockIdx.x*blockDim.x + threadIdx.x; i < total; i += gridDim.x*blockDim.x)
    __hip_atomic_store(w + i, 0u, __ATOMIC_RELAXED, __HIP_MEMORY_SCOPE_AGENT);
}
__global__ void xcvt(const float* __restrict__ x, u64* __restrict__ xh) {
  const int N4 = BB*TT*DIN/4;
  const float4* x4 = reinterpret_cast<const float4*>(x);
  for (int i = blockIdx.x*blockDim.x + threadIdx.x; i < N4; i += gridDim.x*blockDim.x) {
    float4 v = x4[i];
    __half2 a = __floats2half2_rn(v.x, v.y);
    __half2 b = __floats2half2_rn(v.z, v.w);
    u64 u = ((u64)__builtin_bit_cast(unsigned, b) << 32) | (u64)__builtin_bit_cast(unsigned, a);
    __hip_atomic_store(&xh[i], u, __ATOMIC_RELAXED, __HIP_MEMORY_SCOPE_AGENT);
  }
}

// BPG = batches per group. Grid = (64/BPG) groups x 32 WGs.
// BPG=8: 256 WGs, 1/CU (r10-proven). BPG=4: 512 WGs, 2/CU by VGPR (228 regs).
template<int BPG>
__global__ __launch_bounds__(NTHR, 1) void lstm2_k(
    const float* __restrict__ Wih0, const float* __restrict__ Whh0,
    const float* __restrict__ bih0, const float* __restrict__ bhh0,
    const float* __restrict__ Wih1, const float* __restrict__ Whh1,
    const float* __restrict__ bih1, const float* __restrict__ bhh1,
    const float* __restrict__ fcw,  const float* __restrict__ fcb,
    float* __restrict__ out, float* __restrict__ ws)
{
  constexpr int NUNITS = BPG * 144;          // x BPG*16 + h0 BPG*64 + h1 BPG*64
  constexpr int NITER  = (NUNITS + NTHR - 1) / NTHR;
  constexpr int XB     = BPG * 16;           // h0 region base (16B units)
  constexpr int H1B    = XB + BPG * 64;      // h1 region base

  extern __shared__ char smbase[];
  __half* hout = reinterpret_cast<__half*>(smbase + NUNITS*16);  // [2][BPG][16]
  int*    dead = reinterpret_cast<int*>(smbase + NUNITS*16 + 2*BPG*16*2);

  const int tid  = threadIdx.x;
  const int wg   = blockIdx.x;
  const int lane = tid & 63;
  const int wv   = tid >> 6;

  const int grp  = wg >> 5;        // batch group
  const int r    = wg & 31;        // rank -> h-cols [16r,16r+16)
  const int bg   = grp * BPG;
  const int c0   = 16*r + 4*wv;

  __half* h0s = reinterpret_cast<__half*>(ws);     // 2 x [64][512] fp16
  __half* h1s = h0s + 2*BB*HH;
  unsigned* gcnt = reinterpret_cast<unsigned*>(reinterpret_cast<char*>(ws) + 262144) + grp*32;
  const __half* xh = reinterpret_cast<const __half*>(reinterpret_cast<char*>(ws) + 524288);

  // A-fragments, rt = jc*4 + gate (transpose-free epilogue, verified r10)
  const int rt   = lane & 15;
  const int gate = rt & 3;
  const int jc   = rt >> 2;
  const int kg   = lane >> 4;
  const int b15  = lane & 15;
  const int n0   = gate*HH + (c0 + jc);

  f16x8 af0[20];   // L0: K=640 = [x 0-127 | h0 128-639]
#pragma unroll
  for (int m = 0; m < 20; ++m) {
    int k0 = 32*m + 8*kg;
    const float* srcp = (k0 < DIN) ? (Wih0 + (size_t)n0*DIN + k0)
                                   : (Whh0 + (size_t)n0*HH + (k0 - DIN));
    float4 a = *reinterpret_cast<const float4*>(srcp);
    float4 b = *reinterpret_cast<const float4*>(srcp + 4);
    f16x8 fr;
    fr[0]=(_Float16)a.x; fr[1]=(_Float16)a.y; fr[2]=(_Float16)a.z; fr[3]=(_Float16)a.w;
    fr[4]=(_Float16)b.x; fr[5]=(_Float16)b.y; fr[6]=(_Float16)b.z; fr[7]=(_Float16)b.w;
    af0[m] = fr;
  }
  f16x8 af1[32];   // L1: K=1024 = [h0 (W_ih1) | h1 (W_hh1)]
#pragma unroll
  for (int m = 0; m < 32; ++m) {
    int k0 = 32*m + 8*kg;
    const float* srcp = (k0 < HH) ? (Wih1 + (size_t)n0*HH + k0)
                                  : (Whh1 + (size_t)n0*HH + (k0 - HH));
    float4 a = *reinterpret_cast<const float4*>(srcp);
    float4 b = *reinterpret_cast<const float4*>(srcp + 4);
    f16x8 fr;
    fr[0]=(_Float16)a.x; fr[1]=(_Float16)a.y; fr[2]=(_Float16)a.z; fr[3]=(_Float16)a.w;
    fr[4]=(_Float16)b.x; fr[5]=(_Float16)b.y; fr[6]=(_Float16)b.z; fr[7]=(_Float16)b.w;
    af1[m] = fr;
  }

  const int cmy = c0 + kg;
  float bv0[4], bv1[4];
#pragma unroll
  for (int g = 0; g < 4; ++g) {
    bv0[g] = bih0[g*HH + cmy] + bhh0[g*HH + cmy];
    bv1[g] = bih1[g*HH + cmy] + bhh1[g*HH + cmy];
  }

  float cst0 = 0.f, cst1 = 0.f;
  const int beff = (b15 < BPG) ? b15 : (BPG - 1);   // B-frag batch clamp
  if (tid == 0) *dead = 0;
  __syncthreads();

  for (int st = 0; st <= TT; ++st) {
    const int tcur = (st < TT) ? st : (TT - 1);
    const __half* h0r = h0s + (size_t)(st & 1)*BB*HH;
    const __half* h1r = h1s + (size_t)(st & 1)*BB*HH;

    // ---- stage x-slice + group h0 + h1 into LDS (XOR-swizzled) ----
    u32x4 stgL[NITER];
    int   physv[NITER];
#pragma unroll
    for (int ii = 0; ii < NITER; ++ii) {
      int idx = tid + NTHR*ii;
      physv[ii] = -1;
      if (idx < NUNITS) {
        const __half* src; int phys;
        if (idx < XB)       { int b = idx>>4, u = idx&15;
          src = xh + (size_t)(bg+b)*TT*DIN + (size_t)tcur*DIN + u*8;
          phys = b*16 + (u ^ b); }
        else if (idx < H1B) { int i2 = idx-XB,  b = i2>>6, u = i2&63;
          src = h0r + (size_t)(bg+b)*HH + u*8;
          phys = XB + b*64 + (u ^ b); }
        else                { int i2 = idx-H1B, b = i2>>6, u = i2&63;
          src = h1r + (size_t)(bg+b)*HH + u*8;
          phys = H1B + b*64 + (u ^ b); }
        physv[ii] = phys;
        stgL[ii] = ld16m(src);
      }
    }
    asm volatile("s_waitcnt vmcnt(0)" ::: "memory");
    __builtin_amdgcn_sched_barrier(0);
#pragma unroll
    for (int ii = 0; ii < NITER; ++ii)
      if (physv[ii] >= 0)
        *reinterpret_cast<u32x4*>(smbase + physv[ii]*16) = stgL[ii];
    __syncthreads();

    // ---- MFMA: L0 (20) + L1 (32), 2-way acc split ----
    f32x4 a0a = {0.f,0.f,0.f,0.f}, a0b = a0a, a1a = a0a, a1b = a0a;
#pragma unroll
    for (int m = 0; m < 20; ++m) {
      int phys = (m < 4) ? (beff*16 + ((4*m + kg) ^ beff))
                         : (XB + beff*64 + ((4*(m-4) + kg) ^ beff));
      f16x8 bf = *reinterpret_cast<const f16x8*>(smbase + phys*16);
      if (m & 1) a0b = __builtin_amdgcn_mfma_f32_16x16x32_f16(af0[m], bf, a0b, 0, 0, 0);
      else       a0a = __builtin_amdgcn_mfma_f32_16x16x32_f16(af0[m], bf, a0a, 0, 0, 0);
    }
#pragma unroll
    for (int m = 0; m < 32; ++m) {
      int phys = (m < 16) ? (XB + beff*64 + ((4*m + kg) ^ beff))
                          : (H1B + beff*64 + ((4*(m-16) + kg) ^ beff));
      f16x8 bf = *reinterpret_cast<const f16x8*>(smbase + phys*16);
      if (m & 1) a1b = __builtin_amdgcn_mfma_f32_16x16x32_f16(af1[m], bf, a1b, 0, 0, 0);
      else       a1a = __builtin_amdgcn_mfma_f32_16x16x32_f16(af1[m], bf, a1a, 0, 0, 0);
    }
    f32x4 a0 = a0a + a0b;
    f32x4 a1 = a1a + a1b;

    // ---- gates directly from acc (a[j] = gate j of (col cmy, batch b15)) ----
    if (st < TT) {
      float gi = sigm (a0[0] + bv0[0]);
      float gf = sigm (a0[1] + bv0[1]);
      float gg = tanhf(a0[2] + bv0[2]);
      float go = sigm (a0[3] + bv0[3]);
      cst0 = gf*cst0 + gi*gg;
      float hn = go * tanhf(cst0);
      if (b15 < BPG) hout[0*(BPG*16) + b15*16 + 4*wv + kg] = __float2half(hn);
    }
    if (st >= 1) {
      float gi = sigm (a1[0] + bv1[0]);
      float gf = sigm (a1[1] + bv1[1]);
      float gg = tanhf(a1[2] + bv1[2]);
      float go = sigm (a1[3] + bv1[3]);
      cst1 = gf*cst1 + gi*gg;
      float hn = go * tanhf(cst1);
      if (b15 < BPG) hout[1*(BPG*16) + b15*16 + 4*wv + kg] = __float2half(hn);
    }
    __syncthreads();

    // ---- pack-store h (2 layers x BPG batches x 4 parts, 8B each) ----
    if (tid < 2*BPG*4) {
      int layer = tid / (BPG*4), q = tid % (BPG*4), b = q >> 2, part = q & 3;
      bool do_st = (layer == 0) ? (st < TT) : (st >= 1);
      if (do_st) {
        u64 v = *reinterpret_cast<u64*>(hout + layer*(BPG*16) + b*16 + part*4);
        __half* base = (layer ? h1s : h0s) + (size_t)((st + 1) & 1)*BB*HH;
        st8m(base + (size_t)(bg+b)*HH + 16*r + part*4, v);
      }
    }
    gbar(gcnt, 32u*(unsigned)(st + 1), dead);
  }

  // ---- FC on final h1 (parity 1): 4*BPG outputs/WG, TPO threads each ----
  {
    constexpr int TPO = 64 / BPG;          // threads per output (8 or 16)
    constexpr int UPT = 128 / TPO;         // u64 per thread; TPO*UPT = 128 = HH u64s
    const __half* h1f = h1s + (size_t)BB*HH;
    int oi = tid / TPO, kp = tid % TPO;
    int b  = oi >> 2, cc = oi & 3;
    int ocol = 4*r + cc;
    const u64* h8 = reinterpret_cast<const u64*>(h1f + (size_t)(bg+b)*HH) + kp*UPT;
    const float* wrow = fcw + (size_t)ocol*HH + kp*(UPT*4);
    float p = 0.f;
#pragma unroll
    for (int kk = 0; kk < UPT; ++kk) {
      u64 v = ld8m(h8 + kk);
      __half2 hlo = __builtin_bit_cast(__half2, (unsigned)(v & 0xffffffffull));
      __half2 hhi = __builtin_bit_cast(__half2, (unsigned)(v >> 32));
      float2 flo = __half22float2(hlo), fhi = __half22float2(hhi);
      float4 w = *reinterpret_cast<const float4*>(wrow + kk*4);
      p += flo.x*w.x + flo.y*w.y + fhi.x*w.z + fhi.y*w.w;
    }
    p += __shfl_xor(p, 1);
    p += __shfl_xor(p, 2);
    p += __shfl_xor(p, 4);
    if (TPO == 16) p += __shfl_xor(p, 8);
    if (kp == 0 && b < BPG) out[(size_t)(bg+b)*128 + ocol] = p + fcb[ocol];
  }
}

__global__ void sentinel_fail(float* out, float v) { out[threadIdx.x] = v; }

extern "C" void kernel_launch(void* const* d_in, const int* in_sizes, int n_in,
                              void* d_out, int out_size, void* d_ws, size_t ws_size,
                              hipStream_t stream) {
  const float* x    = (const float*)d_in[0];
  const float* Wih0 = (const float*)d_in[1];
  const float* Whh0 = (const float*)d_in[2];
  const float* bih0 = (const float*)d_in[3];
  const float* bhh0 = (const float*)d_in[4];
  const float* Wih1 = (const float*)d_in[5];
  const float* Whh1 = (const float*)d_in[6];
  const float* bih1 = (const float*)d_in[7];
  const float* bhh1 = (const float*)d_in[8];
  const float* fcw  = (const float*)d_in[9];
  const float* fcb  = (const float*)d_in[10];
  float* out = (float*)d_out;
  float* ws  = (float*)d_ws;
  (void)in_sizes; (void)n_in; (void)out_size;

  const size_t need = 524288 + (size_t)BB*TT*DIN*2;
  if (ws_size < need) {
    sentinel_fail<<<1, 128, 0, stream>>>(out, 2.0e6f);
    return;
  }

  const int flush_smem = 108*1024;
  // r15 lesson: ROCm occupancy accounting caps shared mem at 64KB/CU, so a
  // 54KB request reported occ=1 and the TLP path never ran. Request the
  // ACTUAL footprint (16KB >= 9.5KB used); residency cap comes from VGPRs
  // (228 regs -> 2 waves/SIMD -> exactly 2 WGs/CU).
  const int smem4 = 16*1024;
  const int smem8 = 108*1024;   // BPG=8 kernel: forces 1 WG/CU (r10-proven)
  hipFuncSetAttribute(reinterpret_cast<const void*>(&lstm2_k<4>),
                      hipFuncAttributeMaxDynamicSharedMemorySize, smem4);
  hipFuncSetAttribute(reinterpret_cast<const void*>(&lstm2_k<8>),
                      hipFuncAttributeMaxDynamicSharedMemorySize, smem8);
  hipFuncSetAttribute(reinterpret_cast<const void*>(&prep_flush),
                      hipFuncAttributeMaxDynamicSharedMemorySize, flush_smem);

  // Occupancy gate: only take the 512-WG TLP path if >=2 WGs/CU actually fit
  // (VGPR + LDS). Otherwise the proven 256-WG config — never a deadlock.
  int occ = 0;
  hipError_t qe = hipOccupancyMaxActiveBlocksPerMultiprocessor(
      &occ, reinterpret_cast<const void*>(&lstm2_k<4>), NTHR, smem4);
  const bool tlp = (qe == hipSuccess && occ >= 2);

  (void)hipGetLastError();
  prep_flush<<<dim3(256), dim3(64), flush_smem, stream>>>();
  xcvt<<<dim3(2048), dim3(NTHR), 0, stream>>>(
      x, reinterpret_cast<u64*>(reinterpret_cast<char*>(d_ws) + 524288));
  prep_zero<<<dim3(256), dim3(NTHR), 0, stream>>>((unsigned*)d_ws);
  if (tlp)
    lstm2_k<4><<<dim3(512), dim3(NTHR), smem4, stream>>>(
        Wih0, Whh0, bih0, bhh0, Wih1, Whh1, bih1, bhh1, fcw, fcb, out, ws);
  else
    lstm2_k<8><<<dim3(256), dim3(NTHR), smem8, stream>>>(
        Wih0, Whh0, bih0, bhh0, Wih1, Whh1, bih1, bhh1, fcw, fcb, out, ws);
  hipError_t e = hipGetLastError();
  if (e != hipSuccess) {
    sentinel_fail<<<1, 128, 0, stream>>>(out, 1.0e6f);
  }
}